// Round 6
// baseline (681.205 us; speedup 1.0000x reference)
//
#include <hip/hip_runtime.h>
#include <hip/hip_bf16.h>

// Problem dims (fixed by setup_inputs): L=2, B=32, S=2048, D=1024. All floats f32.
constexpr int LAY = 2;
constexpr int BB  = 32;
constexpr int SS  = 2048;
constexpr int DD  = 1024;

typedef unsigned short u16;
typedef short  short8  __attribute__((ext_vector_type(8)));
typedef u16    u16x8   __attribute__((ext_vector_type(8)));
typedef float  floatx4 __attribute__((ext_vector_type(4)));

__device__ inline float bf2f(u16 u) {
    union { unsigned int i; float f; } v; v.i = ((unsigned int)u) << 16; return v.f;
}
__device__ inline u16 f2bf_rn(float f) {
    union { float f; unsigned int i; } v; v.f = f;
    unsigned int x = v.i;
    return (u16)((x + 0x7FFFu + ((x >> 16) & 1u)) >> 16);
}

// Branch-free fast tanh: 1 - 2*rcp(exp(2x)+1).
__device__ __forceinline__ float fast_tanh(float x) {
    float e = __expf(x + x);
    return 1.0f - 2.0f * __builtin_amdgcn_rcpf(e + 1.0f);
}

__device__ __forceinline__ void gload_lds16(const u16* g, u16* l) {
    __builtin_amdgcn_global_load_lds(
        (const __attribute__((address_space(1))) void*)g,
        (__attribute__((address_space(3))) void*)l, 16, 0, 0);
}

// ---------------------------------------------------------------------------
// enc f32 -> bf16 (rn). Grid-stride: 2048 blocks x 256 thr x 16 iters x 8 elems.
__global__ __launch_bounds__(256) void convert_enc(const float* __restrict__ enc,
                                                   u16* __restrict__ encbf) {
    size_t gid = (size_t)blockIdx.x * 256 + threadIdx.x;   // 0..524287
    #pragma unroll 4
    for (int it = 0; it < 16; ++it) {
        size_t i = (it * 524288ull + gid) * 8;
        floatx4 v0 = *reinterpret_cast<const floatx4*>(enc + i);
        floatx4 v1 = *reinterpret_cast<const floatx4*>(enc + i + 4);
        u16x8 r;
        #pragma unroll
        for (int j = 0; j < 4; ++j) { r[j] = f2bf_rn(v0[j]); r[4 + j] = f2bf_rn(v1[j]); }
        *reinterpret_cast<u16x8*>(encbf + i) = r;
    }
}

// W_enc f32 [K][N] -> wt2 bf16, kc-major: wt2[(kc*1024 + n)*8 + j] = W[kc*8+j][n].
// So the 16B unit (kc, n) is contiguous; consecutive n -> contiguous 16B blocks.
// GEMM B-fragment read (quad -> kc, l16 -> n) is then 256B-contiguous per quad.
__global__ __launch_bounds__(256) void transpose_wenc(const float* __restrict__ W,
                                                      u16* __restrict__ wt2) {
    int gid = blockIdx.x * 256 + threadIdx.x;   // 0..131071
    int n = gid & 1023, c = gid >> 10;          // c = kc: 0..127
    u16x8 r;
    #pragma unroll
    for (int j = 0; j < 8; ++j) r[j] = f2bf_rn(W[(size_t)(c * 8 + j) * DD + n]);
    *reinterpret_cast<u16x8*>(&wt2[((size_t)c * DD + n) * 8]) = r;
}

// ---------------------------------------------------------------------------
// dec_proj[b][col] = sum_e h[b][e] * W_dec[e][col] + b_dec[col]
// Grid (16 kc, 4 cb): W_dec read exactly ONCE total (4 MB, was 128 MB).
// h-slice [32][64] staged in LDS; each thread keeps 32 b-accumulators.
__global__ __launch_bounds__(256) void dec_proj_kernel(
    const float* __restrict__ dec_hidden, const float* __restrict__ W_dec,
    const float* __restrict__ b_dec, float* __restrict__ dec_proj) {
    int kc = blockIdx.x, cb = blockIdx.y, t = threadIdx.x;
    int col = cb * 256 + t;
    __shared__ float sh[32][64];
    const float* hbase = dec_hidden + (LAY - 1) * BB * DD + kc * 64;
    #pragma unroll
    for (int j = 0; j < 8; ++j) {
        int idx = t + j * 256;          // 0..2047
        int b = idx >> 6, e = idx & 63;
        sh[b][e] = hbase[(size_t)b * DD + e];
    }
    __syncthreads();
    float acc[32];
    #pragma unroll
    for (int b = 0; b < 32; ++b) acc[b] = 0.f;
    const float* Wp = W_dec + (size_t)kc * 64 * DD + col;
    for (int e = 0; e < 64; ++e) {
        float wv = Wp[(size_t)e * DD];
        #pragma unroll
        for (int b = 0; b < 32; ++b) acc[b] += sh[b][e] * wv;
    }
    float bd = (kc == 0) ? b_dec[col] : 0.f;
    #pragma unroll
    for (int b = 0; b < 32; ++b) atomicAdd(&dec_proj[b * DD + col], acc[b] + bd);
}

// ---------------------------------------------------------------------------
// Fused: E = enc @ W_enc;  scores[r] += sum_n tanh(E[r][n]+dec_proj[b][n]+b_enc[n])*w_att[n]
// v5: BM=64 x BN=256 tile, BK=64, 256 thr = 4 waves (1M x 4N), per-wave C 64x64.
// A staged in LDS (16 KB dbuf only) -> 4 blocks/CU (16 waves) for TLP hiding.
// B read directly from L2-resident wt2 (2 MB, kc-major, coalesced 256B/quad)
// -> LDS/DMA traffic halved (B's 512 MB staged eliminated).
// FIFO vmcnt discipline: b-loads issued BEFORE stage(kt+1), so b-consume waits
// leave the A-prefetch in flight (vmcnt(2), never 0 mid-tile).
// XCD swizzle (T1): 4096 blocks, f%8 = XCD owns contiguous 512-chunk, bn-fast.
__global__ __launch_bounds__(256, 4) void score_gemm_bf(
    const u16* __restrict__ enc,      // [M][K] bf16 row-major
    const u16* __restrict__ wt2,      // [kc][n] 16B units, kc-major
    const float* __restrict__ dec_proj,
    const float* __restrict__ b_enc, const float* __restrict__ w_att,
    float* __restrict__ scores) {
    __shared__ u16 As[2][64 * 64];    // 8 KB each

    const int tid  = threadIdx.x;
    const int f    = blockIdx.x;                 // 0..4095
    const int swz  = ((f & 7) << 9) | (f >> 3);  // bijective (4096 % 8 == 0)
    const int bm   = swz >> 2;                   // 0..1023
    const int bn   = swz & 3;                    // 0..3
    const int row0 = bm * 64, col0 = bn * 256;
    const int lane = tid & 63, w = tid >> 6;     // w: 0..3 (= wn)
    const int quad = lane >> 4, l16 = lane & 15;

    // staging: wave w stages rows [w*16, w*16+16) via 2 instrs of 8 rows.
    // lane l -> row l>>3 within instr, LDS slot l&7, global kchunk (l&7)^(l>>3)
    const int srow = lane >> 3;
    const int scol = (((lane & 7) ^ (lane >> 3)) * 8);

    auto stage = [&](int buf, int kt) {
        const int k0 = kt * 64;
        #pragma unroll
        for (int i = 0; i < 2; ++i)
            gload_lds16(&enc[(size_t)(row0 + w * 16 + i * 8 + srow) * DD + k0 + scol],
                        &As[buf][(w * 16 + i * 8) * 64]);
    };

    floatx4 acc[4][4];
    #pragma unroll
    for (int i = 0; i < 4; ++i)
        #pragma unroll
        for (int j = 0; j < 4; ++j)
            acc[i][j] = (floatx4){0.f, 0.f, 0.f, 0.f};

    // B fragment base: quad -> kc offset, l16 -> n. 16 lanes read 256B contig.
    const u16* bbase = wt2 + ((size_t)quad * DD + col0 + w * 64 + l16) * 8;

    // prologue
    stage(0, 0);
    __syncthreads();

    int buf = 0;
    for (int kt = 0; kt < 16; ++kt) {
        // b-loads first (FIFO: their waits won't drain the A-prefetch)
        short8 b0[4], b1[4];
        const u16* bk = bbase + (size_t)kt * 8 * DD * 8;   // + kt*8 kc rows
        #pragma unroll
        for (int n = 0; n < 4; ++n)
            b0[n] = *reinterpret_cast<const short8*>(bk + (size_t)n * 16 * 8);
        #pragma unroll
        for (int n = 0; n < 4; ++n)
            b1[n] = *reinterpret_cast<const short8*>(bk + (size_t)4 * DD * 8 + (size_t)n * 16 * 8);
        if (kt + 1 < 16) stage(buf ^ 1, kt + 1);
        // ks = 0
        {
            short8 a[4];
            #pragma unroll
            for (int m = 0; m < 4; ++m) {
                int r = m * 16 + l16;
                int kcs = quad ^ (l16 & 7);
                a[m] = *reinterpret_cast<const short8*>(&As[buf][r * 64 + kcs * 8]);
            }
            #pragma unroll
            for (int m = 0; m < 4; ++m)
                #pragma unroll
                for (int n = 0; n < 4; ++n)
                    acc[m][n] = __builtin_amdgcn_mfma_f32_16x16x32_bf16(
                        a[m], b0[n], acc[m][n], 0, 0, 0);
        }
        // ks = 1
        {
            short8 a[4];
            #pragma unroll
            for (int m = 0; m < 4; ++m) {
                int r = m * 16 + l16;
                int kcs = (4 + quad) ^ (l16 & 7);
                a[m] = *reinterpret_cast<const short8*>(&As[buf][r * 64 + kcs * 8]);
            }
            #pragma unroll
            for (int m = 0; m < 4; ++m)
                #pragma unroll
                for (int n = 0; n < 4; ++n)
                    acc[m][n] = __builtin_amdgcn_mfma_f32_16x16x32_bf16(
                        a[m], b1[n], acc[m][n], 0, 0, 0);
        }
        __syncthreads();   // drains own A-prefetch (issued a full phase ago) + join
        buf ^= 1;
    }

    // Epilogue: tanh + dot(w_att) + per-row reduce + atomicAdd
    // C/D layout (m89/m91-verified): col = lane&15, row = quad*4 + reg
    const int bIdx = row0 / SS;
    const float* dp = dec_proj + bIdx * DD;
    float cvec[4], wvv[4];
    #pragma unroll
    for (int tn = 0; tn < 4; ++tn) {
        int n = col0 + w * 64 + tn * 16 + l16;
        cvec[tn] = dp[n] + b_enc[n];
        wvv[tn]  = w_att[n];
    }
    #pragma unroll
    for (int tm = 0; tm < 4; ++tm) {
        float rs0 = 0.f, rs1 = 0.f, rs2 = 0.f, rs3 = 0.f;
        #pragma unroll
        for (int tn = 0; tn < 4; ++tn) {
            rs0 += fast_tanh(acc[tm][tn][0] + cvec[tn]) * wvv[tn];
            rs1 += fast_tanh(acc[tm][tn][1] + cvec[tn]) * wvv[tn];
            rs2 += fast_tanh(acc[tm][tn][2] + cvec[tn]) * wvv[tn];
            rs3 += fast_tanh(acc[tm][tn][3] + cvec[tn]) * wvv[tn];
        }
        #pragma unroll
        for (int off = 1; off < 16; off <<= 1) {
            rs0 += __shfl_xor(rs0, off, 64);
            rs1 += __shfl_xor(rs1, off, 64);
            rs2 += __shfl_xor(rs2, off, 64);
            rs3 += __shfl_xor(rs3, off, 64);
        }
        if (l16 == 0) {
            int rbase = row0 + tm * 16 + quad * 4;
            atomicAdd(&scores[rbase + 0], rs0);
            atomicAdd(&scores[rbase + 1], rs1);
            atomicAdd(&scores[rbase + 2], rs2);
            atomicAdd(&scores[rbase + 3], rs3);
        }
    }
}

// ---------------------------------------------------------------------------
// Masked softmax over S per b. b_att omitted (shift-invariant).
__global__ __launch_bounds__(256) void softmax_kernel(
    const float* __restrict__ scores, const int* __restrict__ mask,
    float* __restrict__ attn_out) {
    int b = blockIdx.x, t = threadIdx.x;
    const float* srow = scores + b * SS;
    const int*   mrow = mask + b * SS;
    float vals[8];
    float vmax = -1e30f;
    #pragma unroll
    for (int i = 0; i < 8; ++i) {
        int s = i * 256 + t;
        float v = (mrow[s] == 0) ? -1e10f : srow[s];
        vals[i] = v;
        vmax = fmaxf(vmax, v);
    }
    #pragma unroll
    for (int off = 32; off >= 1; off >>= 1) vmax = fmaxf(vmax, __shfl_xor(vmax, off, 64));
    __shared__ float sm[4];
    if ((t & 63) == 0) sm[t >> 6] = vmax;
    __syncthreads();
    vmax = fmaxf(fmaxf(sm[0], sm[1]), fmaxf(sm[2], sm[3]));
    float sum = 0.f;
    #pragma unroll
    for (int i = 0; i < 8; ++i) { vals[i] = __expf(vals[i] - vmax); sum += vals[i]; }
    #pragma unroll
    for (int off = 32; off >= 1; off >>= 1) sum += __shfl_xor(sum, off, 64);
    __shared__ float ssum[4];
    if ((t & 63) == 0) ssum[t >> 6] = sum;
    __syncthreads();
    sum = ssum[0] + ssum[1] + ssum[2] + ssum[3];
    float inv = 1.f / sum;
    #pragma unroll
    for (int i = 0; i < 8; ++i) attn_out[b * SS + i * 256 + t] = vals[i] * inv;
}

// ---------------------------------------------------------------------------
// ctx[b][d..d+7] += sum_s attn[b][s] * encbf[b][s][d..d+7]
// 1024 blocks (32 s-chunks x 32 b), 16 B/lane loads, 4 blocks/CU.
__global__ __launch_bounds__(256) void context_bf(
    const float* __restrict__ attn, const u16* __restrict__ encbf,
    float* __restrict__ ctx) {
    int scb = blockIdx.x;   // 0..31
    int b   = blockIdx.y;   // 0..31
    int t   = threadIdx.x;
    int d   = (t & 127) * 8;            // 8 bf16 per thread -> 128 thr cover a row
    int sh  = t >> 7;                   // waves 0,1: even s; waves 2,3: odd s
    const float* ar  = attn + b * SS + scb * 64;
    const u16*  base = encbf + ((size_t)b * SS + scb * 64) * DD + d;
    float a[8];
    #pragma unroll
    for (int j = 0; j < 8; ++j) a[j] = 0.f;
    #pragma unroll 4
    for (int so = 0; so < 64; so += 2) {
        int s = so + sh;
        u16x8 v = *reinterpret_cast<const u16x8*>(base + (size_t)s * DD);
        float w = ar[s];
        #pragma unroll
        for (int j = 0; j < 8; ++j) a[j] += w * bf2f(v[j]);
    }
    #pragma unroll
    for (int j = 0; j < 8; ++j) atomicAdd(&ctx[b * DD + d + j], a[j]);
}

// ---------------------------------------------------------------------------
extern "C" void kernel_launch(void* const* d_in, const int* in_sizes, int n_in,
                              void* d_out, int out_size, void* d_ws, size_t ws_size,
                              hipStream_t stream) {
    const float* dec_hidden = (const float*)d_in[0];
    const float* enc        = (const float*)d_in[1];
    const int*   mask       = (const int*)d_in[2];
    const float* W_dec      = (const float*)d_in[3];
    const float* b_dec      = (const float*)d_in[4];
    const float* W_enc      = (const float*)d_in[5];
    const float* b_enc      = (const float*)d_in[6];
    const float* w_att      = (const float*)d_in[7];
    // d_in[8] (b_att): uniform shift into softmax -> no effect, omitted.

    float* out = (float*)d_out;               // [0,32768) context ; [32768,98304) attn
    float* ws  = (float*)d_ws;
    float* dec_proj = ws;                     // 32768 f32
    float* scores   = ws + 32768;             // 65536 f32
    u16*   wt2      = (u16*)(ws + 98304);     // 1M bf16 (2 MB), kc-major
    u16*   encbf    = (u16*)(ws + 622592);    // 64M bf16 (128 MB)
    float* attn     = out + 32768;

    hipMemsetAsync(ws, 0, 98304 * sizeof(float), stream);
    hipMemsetAsync(out, 0, 32768 * sizeof(float), stream);

    convert_enc<<<2048, 256, 0, stream>>>(enc, encbf);
    transpose_wenc<<<512, 256, 0, stream>>>(W_enc, wt2);
    dec_proj_kernel<<<dim3(16, 4), 256, 0, stream>>>(dec_hidden, W_dec, b_dec, dec_proj);
    score_gemm_bf<<<4096, 256, 0, stream>>>(encbf, wt2, dec_proj, b_enc, w_att, scores);
    softmax_kernel<<<32, 256, 0, stream>>>(scores, mask, attn);
    context_bf<<<dim3(32, 32), 256, 0, stream>>>(attn, encbf, out);
}